// Round 11
// baseline (1508.984 us; speedup 1.0000x reference)
//
#include <hip/hip_runtime.h>

#define NB_ 16
#define TQ_ 2048
#define TS_ 2048
#define DH_ 1024
#define QB_ 16
#define SB_ 128
#define NT_ 512

typedef _Float16 f16x8 __attribute__((ext_vector_type(8)));
typedef _Float16 f16x4 __attribute__((ext_vector_type(4)));
typedef float f32x4 __attribute__((ext_vector_type(4)));

// LDS-domain barrier: does NOT drain vmcnt; in-flight global loads survive.
#define LDS_BARRIER() asm volatile("s_waitcnt lgkmcnt(0)\n\ts_barrier" ::: "memory")

__global__ void convert_f32_f16(const float* __restrict__ src, _Float16* __restrict__ dst) {
  size_t i = ((size_t)blockIdx.x * blockDim.x + threadIdx.x) * 8;
  float4 v0 = *(const float4*)(src + i);
  float4 v1 = *(const float4*)(src + i + 4);
  f16x8 o;
  o[0] = (_Float16)v0.x; o[1] = (_Float16)v0.y; o[2] = (_Float16)v0.z; o[3] = (_Float16)v0.w;
  o[4] = (_Float16)v1.x; o[5] = (_Float16)v1.y; o[6] = (_Float16)v1.z; o[7] = (_Float16)v1.w;
  *(f16x8*)(dst + i) = o;
}

__device__ inline f16x8 cvt8(const float* __restrict__ fp) {
  float4 a = *(const float4*)fp;
  float4 b = *(const float4*)(fp + 4);
  f16x8 t;
  t[0] = (_Float16)a.x; t[1] = (_Float16)a.y; t[2] = (_Float16)a.z; t[3] = (_Float16)a.w;
  t[4] = (_Float16)b.x; t[5] = (_Float16)b.y; t[6] = (_Float16)b.z; t[7] = (_Float16)b.w;
  return t;
}

template<bool WS16>
__device__ inline f16x8 ld8(const _Float16* __restrict__ hp, const float* __restrict__ fp, size_t idx) {
  if constexpr (WS16) return *(const f16x8*)(hp + idx);
  else return cvt8(fp + idx);
}

// LDS layout (bytes), total 71872 -> 2 WGs/CU (16 waves/CU):
//   vt     : 0     .. 32768   8 x 4096 per-wave V-transpose [64 h][32 s]   [v6-verified]
//            byte = (h*64 + s*2) ^ (((h>>3)&7)<<4)
//   s_tiles: 32768 .. 67584   8 tiles [(sh*4+dw)][16 q][68] f32 (partial S over d-chunk)
//   p_base : 67584 .. 71680   P [16 q][128 s] f16, byte=(q*256+s*2)^((q&7)<<4)
//   m/l/c  : 71680 .. 71872   softmax state (16 q each)
template<bool WS16>
__global__ __launch_bounds__(NT_, 4)   // 4 waves/EU -> 2 WGs/CU; cap 128 total regs/wave
void attn_v11(const float* __restrict__ hid,
              const float* __restrict__ enc,
              const _Float16* __restrict__ encH,
              float* __restrict__ out) {
  __shared__ __attribute__((aligned(16))) char smem[71872];
  char*  const vt_all  = smem;
  float* const s_tiles = (float*)(smem + 32768);
  char*  const p_base  = smem + 67584;
  float* const m_lds   = (float*)(smem + 71680);
  float* const l_lds   = m_lds + 16;
  float* const c_lds   = m_lds + 32;

  const int tid  = threadIdx.x;
  const int lane = tid & 63;
  const int wid  = tid >> 6;
  const int arow = lane & 15;
  const int agrp = lane >> 4;

  // XCD-affine: XCD x sweeps all 128 q-tiles of batch x, then batch x+8.
  const int bi  = blockIdx.x;
  const int x   = bi & 7;
  const int idx = bi >> 3;            // 0..255
  const int b   = x + 8 * (idx >> 7);
  const int q0  = (idx & 127) * QB_;

  const int dw = wid & 3;   // QK^T d-chunk (256 wide)
  const int sh = wid >> 2;  // QK^T s-half (64 wide)
  const int hw = wid;       // PV h-chunk (128 wide), 2 rounds of 64

  if (tid < 16) { m_lds[tid] = -__builtin_inff(); l_lds[tid] = 0.0f; }

  // ---- Q fragments in registers (persistent, 32 VGPR) ----
  f16x8 a_q[8];
  #pragma unroll
  for (int kf = 0; kf < 8; ++kf) {
    const float* qp = hid + ((size_t)(b * TQ_ + q0 + arow)) * DH_
                          + dw * 256 + kf * 32 + agrp * 8;
    a_q[kf] = cvt8(qp);
  }

  f32x4 o_acc[2][4];   // [h-round][n] = 32 AGPR persistent
  #pragma unroll
  for (int r = 0; r < 2; ++r)
    #pragma unroll
    for (int n = 0; n < 4; ++n)
      o_acc[r][n] = {};

  char* const vt = vt_all + wid * 4096;
  const size_t enc_b = (size_t)b * TS_ * DH_;
  const int c8 = (lane & 7) * 8;        // V staging h-octet (within 64)
  const int d2 = (lane >> 3) * 2;       // V staging s-pair base (0..14)

  for (int st = 0; st < TS_ / SB_; ++st) {
    const int s0 = st * SB_;

    // ================= QK^T: partial S[16q][64s] over d-chunk dw =================
    f32x4 sacc[4] = {{}, {}, {}, {}};
    #pragma unroll
    for (int kf = 0; kf < 8; ++kf) {
      const int d = dw * 256 + kf * 32 + agrp * 8;
      f16x8 bf[4];
      #pragma unroll
      for (int n = 0; n < 4; ++n) {
        size_t kb = enc_b + (size_t)(s0 + sh * 64 + n * 16 + arow) * DH_ + d;
        bf[n] = ld8<WS16>(encH, enc, kb);
      }
      #pragma unroll
      for (int n = 0; n < 4; ++n)
        sacc[n] = __builtin_amdgcn_mfma_f32_16x16x32_f16(a_q[kf], bf[n], sacc[n], 0, 0, 0);
    }

    // ---- issue PV pass-0 V loads (in flight across both barriers) ----
    // pass 0 = h-round 0, s-phase 0: V[s0 .. s0+31][hw*128 .. +63]
    f16x8 stgA[2][2], stgB[2][2];
    #pragma unroll
    for (int it = 0; it < 2; ++it) {
      size_t base = enc_b + (size_t)(s0 + it * 16 + d2) * DH_ + hw * 128 + c8;
      stgA[it][0] = ld8<WS16>(encH, enc, base);
      stgA[it][1] = ld8<WS16>(encH, enc, base + DH_);
    }

    // write partial S tile (sh*4+dw): [16 q][68] f32
    {
      float* tp = s_tiles + (size_t)(sh * 4 + dw) * (16 * 68);
      #pragma unroll
      for (int n = 0; n < 4; ++n)
        #pragma unroll
        for (int i2 = 0; i2 < 4; ++i2)
          tp[(agrp * 4 + i2) * 68 + n * 16 + arow] = sacc[n][i2];
    }

    LDS_BARRIER();  // b1: S complete (V loads stay in flight)

    // ================= online softmax over [16 q][128 s]: 32 threads/row =================
    {
      int q = tid >> 5, sq = tid & 31;             // row q, thread covers s = sq*4..+3
      int shh = sq >> 4, sc = (sq & 15) * 4;       // which s-half tile, col within
      const float* bp = s_tiles + (size_t)shh * 4 * (16 * 68) + q * 68 + sc;
      f32x4 v = *(const f32x4*)bp;                 // dw=0..3 partials at stride 16*68
      v += *(const f32x4*)(bp + 1088);
      v += *(const f32x4*)(bp + 2176);
      v += *(const f32x4*)(bp + 3264);
      float mx = fmaxf(fmaxf(v[0], v[1]), fmaxf(v[2], v[3]));
      #pragma unroll
      for (int o = 16; o; o >>= 1) mx = fmaxf(mx, __shfl_xor(mx, o));
      float mprev = m_lds[q];
      float mnew  = fmaxf(mprev, mx);
      float p0 = __expf(v[0] - mnew), p1 = __expf(v[1] - mnew);
      float p2 = __expf(v[2] - mnew), p3 = __expf(v[3] - mnew);
      float ps = (p0 + p1) + (p2 + p3);
      #pragma unroll
      for (int o = 16; o; o >>= 1) ps += __shfl_xor(ps, o);
      if (sq == 0) {
        float cf = __expf(mprev - mnew);
        m_lds[q] = mnew;
        l_lds[q] = l_lds[q] * cf + ps;
        c_lds[q] = cf;
      }
      f16x4 pw;
      pw[0] = (_Float16)p0; pw[1] = (_Float16)p1;
      pw[2] = (_Float16)p2; pw[3] = (_Float16)p3;
      *(f16x4*)(p_base + ((q * 256 + sq * 8) ^ ((q & 7) << 4))) = pw;
    }

    LDS_BARRIER();  // b2: P + m/l/c complete

    // ---- rescale O ----
    #pragma unroll
    for (int i2 = 0; i2 < 4; ++i2) {
      float cf = c_lds[agrp * 4 + i2];
      #pragma unroll
      for (int r = 0; r < 2; ++r)
        #pragma unroll
        for (int n = 0; n < 4; ++n)
          o_acc[r][n][i2] *= cf;
    }

    // ================= PV: 8 passes (h-round r = pass>>2, s-phase sp = pass&3) =================
    #pragma unroll
    for (int pass = 0; pass < 8; ++pass) {
      const int r  = pass >> 2, sp = pass & 3;
      const bool useA = (pass & 1) == 0;
      // write Vt from current buffer (wave-private, DS in-order, no barrier)
      #pragma unroll
      for (int it = 0; it < 2; ++it) {
        int sl = it * 16 + d2;
        #pragma unroll
        for (int jj = 0; jj < 8; ++jj) {
          int hl = c8 + jj;
          union { _Float16 h[2]; uint32_t u; } pk;
          pk.h[0] = useA ? stgA[it][0][jj] : stgB[it][0][jj];
          pk.h[1] = useA ? stgA[it][1][jj] : stgB[it][1][jj];
          *(uint32_t*)(vt + ((hl * 64 + sl * 2) ^ (((hl >> 3) & 7) << 4))) = pk.u;
        }
      }
      // issue next pass's V loads into the other buffer (overlap with MFMAs below)
      if (pass < 7) {
        const int rn = (pass + 1) >> 2, spn = (pass + 1) & 3;
        #pragma unroll
        for (int it = 0; it < 2; ++it) {
          size_t base = enc_b + (size_t)(s0 + spn * 32 + it * 16 + d2) * DH_
                        + hw * 128 + rn * 64 + c8;
          if (useA) {  // next uses B
            stgB[it][0] = ld8<WS16>(encH, enc, base);
            stgB[it][1] = ld8<WS16>(encH, enc, base + DH_);
          } else {
            stgA[it][0] = ld8<WS16>(encH, enc, base);
            stgA[it][1] = ld8<WS16>(encH, enc, base + DH_);
          }
        }
      }
      // P A-frag for this s-phase
      f16x8 paf = *(const f16x8*)(p_base +
          ((arow * 256 + sp * 64 + agrp * 16) ^ ((arow & 7) << 4)));
      __builtin_amdgcn_s_setprio(1);
      #pragma unroll
      for (int n = 0; n < 4; ++n) {
        int hl = n * 16 + arow;
        f16x8 bv = *(const f16x8*)(vt + ((hl * 64 + agrp * 16) ^ (((hl >> 3) & 7) << 4)));
        o_acc[r][n] = __builtin_amdgcn_mfma_f32_16x16x32_f16(paf, bv, o_acc[r][n], 0, 0, 0);
      }
      __builtin_amdgcn_s_setprio(0);
    }
  }

  // ================= epilogue: O / l =================
  #pragma unroll
  for (int i2 = 0; i2 < 4; ++i2) {
    int qr = agrp * 4 + i2;
    float inv = 1.0f / l_lds[qr];
    #pragma unroll
    for (int r = 0; r < 2; ++r)
      #pragma unroll
      for (int n = 0; n < 4; ++n)
        out[((size_t)(b * TQ_ + q0 + qr)) * DH_ + hw * 128 + r * 64 + n * 16 + arow] =
            o_acc[r][n][i2] * inv;
  }
}

extern "C" void kernel_launch(void* const* d_in, const int* in_sizes, int n_in,
                              void* d_out, int out_size, void* d_ws, size_t ws_size,
                              hipStream_t stream) {
  (void)in_sizes; (void)n_in; (void)out_size;
  const float* hid = (const float*)d_in[0];
  const float* enc = (const float*)d_in[1];
  float* out = (float*)d_out;

  const size_t encN = (size_t)NB_ * TS_ * DH_;
  const bool ws16 = (ws_size >= encN * sizeof(_Float16));

  dim3 grid(NB_ * (TQ_ / QB_), 1, 1);   // 2048 WGs
  dim3 block(NT_, 1, 1);

  if (ws16) {
    _Float16* encH = (_Float16*)d_ws;
    convert_f32_f16<<<dim3((unsigned)(encN / 8 / 256)), dim3(256), 0, stream>>>(enc, encH);
    attn_v11<true><<<grid, block, 0, stream>>>(hid, enc, encH, out);
  } else {
    attn_v11<false><<<grid, block, 0, stream>>>(hid, enc, nullptr, out);
  }
}

// Round 12
// 741.939 us; speedup vs baseline: 2.0338x; 2.0338x over previous
//
#include <hip/hip_runtime.h>

#define NB_ 16
#define TQ_ 2048
#define TS_ 2048
#define DH_ 1024
#define QB_ 32
#define SB_ 256
#define NT_ 512

typedef _Float16 f16x8 __attribute__((ext_vector_type(8)));
typedef _Float16 f16x4 __attribute__((ext_vector_type(4)));
typedef float f32x4 __attribute__((ext_vector_type(4)));

__device__ inline uint32_t pack_h2(float a, float b) {
  union { _Float16 h[2]; uint32_t u; } c;
  c.h[0] = (_Float16)a; c.h[1] = (_Float16)b;
  return c.u;
}

__global__ void convert_f32_f16(const float* __restrict__ src, _Float16* __restrict__ dst) {
  size_t i = ((size_t)blockIdx.x * blockDim.x + threadIdx.x) * 8;
  float4 v0 = *(const float4*)(src + i);
  float4 v1 = *(const float4*)(src + i + 4);
  f16x8 o;
  o[0] = (_Float16)v0.x; o[1] = (_Float16)v0.y; o[2] = (_Float16)v0.z; o[3] = (_Float16)v0.w;
  o[4] = (_Float16)v1.x; o[5] = (_Float16)v1.y; o[6] = (_Float16)v1.z; o[7] = (_Float16)v1.w;
  *(f16x8*)(dst + i) = o;
}

__device__ inline f16x8 cvt8(const float* __restrict__ fp) {
  float4 a = *(const float4*)fp;
  float4 b = *(const float4*)(fp + 4);
  f16x8 t;
  t[0] = (_Float16)a.x; t[1] = (_Float16)a.y; t[2] = (_Float16)a.z; t[3] = (_Float16)a.w;
  t[4] = (_Float16)b.x; t[5] = (_Float16)b.y; t[6] = (_Float16)b.z; t[7] = (_Float16)b.w;
  return t;
}

template<bool WS16>
__device__ inline f16x8 ld8(const _Float16* __restrict__ hp, const float* __restrict__ fp, size_t idx) {
  if constexpr (WS16) return *(const f16x8*)(hp + idx);
  else return cvt8(fp + idx);
}

// LDS layout (bytes), total 148352 (<160 KiB, 1 WG/CU):
//   q_base : 0      .. 65536   Q [32 q][1024 d] f16, byte=(q*2048+d*2)^((q&7)<<4)  [v8-verified]
//   s_lds  : 65536  .. 98816   S f32 [32 q][260]  (single-writer full S tile)
//   p_base : 98816  .. 115200  P [32 q][256 s] f16, byte=(q*512+s*2)^((q&7)<<4)
//   vt     : 115200 .. 147968  8 x 4096 per-wave V-transpose [64 h][32 s]  [v6-verified]
//            byte = (h*64 + s*2) ^ (((h>>3)&7)<<4)
//   m/l/c  : 147968 .. 148352  softmax state
template<bool WS16>
__global__ __launch_bounds__(NT_, 2)
void attn_v12(const float* __restrict__ hid,
              const float* __restrict__ enc,
              const _Float16* __restrict__ encH,
              float* __restrict__ out) {
  __shared__ __attribute__((aligned(16))) char smem[148352];
  char*  const q_base = smem;
  float* const s_lds  = (float*)(smem + 65536);
  char*  const p_base = smem + 98816;
  char*  const vt_all = smem + 115200;
  float* const m_lds  = (float*)(smem + 147968);
  float* const l_lds  = m_lds + 32;
  float* const c_lds  = m_lds + 64;

  const int tid  = threadIdx.x;
  const int lane = tid & 63;
  const int wid  = tid >> 6;
  const int arow = lane & 15;
  const int agrp = lane >> 4;

  // XCD-affine: XCD x sweeps all 64 q-tiles of batch x, then batch x+8.
  const int bi  = blockIdx.x;
  const int x   = bi & 7;
  const int idx = bi >> 3;
  const int b   = x + 8 * (idx >> 6);
  const int q0  = (idx & 63) * QB_;

  const int hw = wid;  // PV h-chunk (128 wide); QK^T s-chunk = wid*32

  if (tid < 32) { m_lds[tid] = -__builtin_inff(); l_lds[tid] = 0.0f; }

  // ---- stage Q (32 x 1024) fp32 -> f16 into LDS, swizzled (v8-verified) ----
  {
    const float* qsrc = hid + ((size_t)b * TQ_ + q0) * DH_;
    #pragma unroll
    for (int k = 0; k < 16; ++k) {
      int i = tid + k * NT_;
      int q = i >> 8;
      int h = (i & 255) * 4;
      float4 v = *(const float4*)(qsrc + (size_t)q * DH_ + h);
      int byte = (q * 2048 + h * 2) ^ ((q & 7) << 4);
      *(uint32_t*)(q_base + byte)     = pack_h2(v.x, v.y);
      *(uint32_t*)(q_base + byte + 4) = pack_h2(v.z, v.w);
    }
  }
  __syncthreads();

  f32x4 o_acc[2][8];   // [m][j]; j = r*4+n over 128 h  (64 AGPR persistent)
  #pragma unroll
  for (int m = 0; m < 2; ++m)
    #pragma unroll
    for (int n = 0; n < 8; ++n)
      o_acc[m][n] = {};

  char* const vt = vt_all + wid * 4096;
  const size_t enc_b = (size_t)b * TS_ * DH_;
  const int c8 = (lane & 7) * 8;        // V staging h-octet (within 64)
  const int d2 = (lane >> 3) * 2;       // V staging s-pair base

  for (int st = 0; st < TS_ / SB_; ++st) {
    const int s0 = st * SB_;

    // ================= QK^T: wave computes full-d S[32q][32s], s-chunk = wid*32 =================
    // Each Q-frag (af0/af1) read ONCE per kf feeds BOTH s-subtiles (bf0/bf1): Q-DS halved vs v8.
    f32x4 sacc[2][2] = {{{}, {}}, {{}, {}}};   // [m][n-subtile]
    {
      const size_t krow = enc_b + (size_t)(s0 + wid * 32 + arow) * DH_;
      #pragma unroll
      for (int kf = 0; kf < 32; ++kf) {
        const int d = kf * 32 + agrp * 8;
        f16x8 bf0 = ld8<WS16>(encH, enc, krow + d);
        f16x8 bf1 = ld8<WS16>(encH, enc, krow + (size_t)16 * DH_ + d);
        f16x8 af0 = *(const f16x8*)(q_base + ((arow * 2048 + d * 2) ^ ((arow & 7) << 4)));
        f16x8 af1 = *(const f16x8*)(q_base + (((16 + arow) * 2048 + d * 2) ^ ((arow & 7) << 4)));
        sacc[0][0] = __builtin_amdgcn_mfma_f32_16x16x32_f16(af0, bf0, sacc[0][0], 0, 0, 0);
        sacc[0][1] = __builtin_amdgcn_mfma_f32_16x16x32_f16(af0, bf1, sacc[0][1], 0, 0, 0);
        sacc[1][0] = __builtin_amdgcn_mfma_f32_16x16x32_f16(af1, bf0, sacc[1][0], 0, 0, 0);
        sacc[1][1] = __builtin_amdgcn_mfma_f32_16x16x32_f16(af1, bf1, sacc[1][1], 0, 0, 0);
      }
    }

    // ---- issue PV pass-0 V loads (v8 position: arrive during S-write + softmax + barriers) ----
    f16x8 stgA[2][2], stgB[2][2];
    #pragma unroll
    for (int it = 0; it < 2; ++it) {
      size_t base = enc_b + (size_t)(s0 + it * 16 + d2) * DH_ + hw * 128 + c8;
      stgA[it][0] = ld8<WS16>(encH, enc, base);
      stgA[it][1] = ld8<WS16>(encH, enc, base + DH_);
    }

    // write S tile (single writer per element): rows m*16+agrp*4+i2, col wid*32 + n*16 + arow
    {
      const int sc = wid * 32 + arow;
      #pragma unroll
      for (int m = 0; m < 2; ++m)
        #pragma unroll
        for (int n = 0; n < 2; ++n)
          #pragma unroll
          for (int i2 = 0; i2 < 4; ++i2)
            s_lds[(m * 16 + agrp * 4 + i2) * 260 + sc + n * 16] = sacc[m][n][i2];
    }

    __syncthreads();  // b1: S complete

    // ================= online softmax over [32 q][256 s]: 16 threads/row, 16 s each =================
    {
      int q = tid >> 4, sq = tid & 15;
      const float* bp = s_lds + q * 260 + sq * 16;
      f32x4 v0 = *(const f32x4*)bp;
      f32x4 v1 = *(const f32x4*)(bp + 4);
      f32x4 v2 = *(const f32x4*)(bp + 8);
      f32x4 v3 = *(const f32x4*)(bp + 12);
      f32x4 vm = v0;
      #pragma unroll
      for (int j = 0; j < 4; ++j) { vm[j] = fmaxf(fmaxf(v0[j], v1[j]), fmaxf(v2[j], v3[j])); }
      float mx = fmaxf(fmaxf(vm[0], vm[1]), fmaxf(vm[2], vm[3]));
      #pragma unroll
      for (int o = 8; o; o >>= 1) mx = fmaxf(mx, __shfl_xor(mx, o));
      float mprev = m_lds[q];
      float mnew  = fmaxf(mprev, mx);
      float p[16], ps = 0.0f;
      #pragma unroll
      for (int j = 0; j < 4; ++j) {
        p[j]      = __expf(v0[j] - mnew);
        p[4 + j]  = __expf(v1[j] - mnew);
        p[8 + j]  = __expf(v2[j] - mnew);
        p[12 + j] = __expf(v3[j] - mnew);
      }
      #pragma unroll
      for (int j = 0; j < 16; ++j) ps += p[j];
      #pragma unroll
      for (int o = 8; o; o >>= 1) ps += __shfl_xor(ps, o);
      if (sq == 0) {
        float cf = __expf(mprev - mnew);
        m_lds[q] = mnew;
        l_lds[q] = l_lds[q] * cf + ps;
        c_lds[q] = cf;
      }
      #pragma unroll
      for (int g = 0; g < 4; ++g) {
        f16x4 pw;
        pw[0] = (_Float16)p[g * 4 + 0]; pw[1] = (_Float16)p[g * 4 + 1];
        pw[2] = (_Float16)p[g * 4 + 2]; pw[3] = (_Float16)p[g * 4 + 3];
        *(f16x4*)(p_base + ((q * 512 + sq * 32 + g * 8) ^ ((q & 7) << 4))) = pw;
      }
    }

    __syncthreads();  // b2: P + m/l/c complete

    // ---- rescale O ----
    #pragma unroll
    for (int m = 0; m < 2; ++m)
      #pragma unroll
      for (int i2 = 0; i2 < 4; ++i2) {
        float cf = c_lds[m * 16 + agrp * 4 + i2];
        #pragma unroll
        for (int n = 0; n < 8; ++n) o_acc[m][n][i2] *= cf;
      }

    // ================= PV: 16 passes (h-round r = pass>>3, s-phase sp = pass&7) =================
    #pragma unroll
    for (int pass = 0; pass < 16; ++pass) {
      const int r  = pass >> 3, sp = pass & 7;
      const bool useA = (pass & 1) == 0;
      // write Vt from current buffer (wave-private, DS in-order, no barrier)
      #pragma unroll
      for (int it = 0; it < 2; ++it) {
        int sl = it * 16 + d2;
        #pragma unroll
        for (int jj = 0; jj < 8; ++jj) {
          int hl = c8 + jj;
          union { _Float16 h[2]; uint32_t u; } pk;
          pk.h[0] = useA ? stgA[it][0][jj] : stgB[it][0][jj];
          pk.h[1] = useA ? stgA[it][1][jj] : stgB[it][1][jj];
          *(uint32_t*)(vt + ((hl * 64 + sl * 2) ^ (((hl >> 3) & 7) << 4))) = pk.u;
        }
      }
      // issue next pass's V loads into the other buffer (overlap with MFMAs below)
      if (pass < 15) {
        const int rn = (pass + 1) >> 3, spn = (pass + 1) & 7;
        #pragma unroll
        for (int it = 0; it < 2; ++it) {
          size_t base = enc_b + (size_t)(s0 + spn * 32 + it * 16 + d2) * DH_
                        + hw * 128 + rn * 64 + c8;
          if (useA) {
            stgB[it][0] = ld8<WS16>(encH, enc, base);
            stgB[it][1] = ld8<WS16>(encH, enc, base + DH_);
          } else {
            stgA[it][0] = ld8<WS16>(encH, enc, base);
            stgA[it][1] = ld8<WS16>(encH, enc, base + DH_);
          }
        }
      }
      // P A-frags for this s-phase
      f16x8 paf0 = *(const f16x8*)(p_base +
          ((arow * 512 + sp * 64 + agrp * 16) ^ ((arow & 7) << 4)));
      f16x8 paf1 = *(const f16x8*)(p_base +
          (((16 + arow) * 512 + sp * 64 + agrp * 16) ^ ((arow & 7) << 4)));
      __builtin_amdgcn_s_setprio(1);
      #pragma unroll
      for (int n = 0; n < 4; ++n) {
        int hl = n * 16 + arow;
        f16x8 bv = *(const f16x8*)(vt + ((hl * 64 + agrp * 16) ^ (((hl >> 3) & 7) << 4)));
        o_acc[0][r * 4 + n] = __builtin_amdgcn_mfma_f32_16x16x32_f16(paf0, bv, o_acc[0][r * 4 + n], 0, 0, 0);
        o_acc[1][r * 4 + n] = __builtin_amdgcn_mfma_f32_16x16x32_f16(paf1, bv, o_acc[1][r * 4 + n], 0, 0, 0);
      }
      __builtin_amdgcn_s_setprio(0);
    }
  }

  // ================= epilogue: O / l =================
  #pragma unroll
  for (int m = 0; m < 2; ++m) {
    #pragma unroll
    for (int i2 = 0; i2 < 4; ++i2) {
      int qr = m * 16 + agrp * 4 + i2;
      float inv = 1.0f / l_lds[qr];
      #pragma unroll
      for (int n = 0; n < 8; ++n) {
        out[((size_t)(b * TQ_ + q0 + qr)) * DH_ + hw * 128 + (n >> 2) * 64 + (n & 3) * 16 + arow] =
            o_acc[m][n][i2] * inv;
      }
    }
  }
}

extern "C" void kernel_launch(void* const* d_in, const int* in_sizes, int n_in,
                              void* d_out, int out_size, void* d_ws, size_t ws_size,
                              hipStream_t stream) {
  (void)in_sizes; (void)n_in; (void)out_size;
  const float* hid = (const float*)d_in[0];
  const float* enc = (const float*)d_in[1];
  float* out = (float*)d_out;

  const size_t encN = (size_t)NB_ * TS_ * DH_;
  const bool ws16 = (ws_size >= encN * sizeof(_Float16));

  dim3 grid(NB_ * (TQ_ / QB_), 1, 1);
  dim3 block(NT_, 1, 1);

  if (ws16) {
    _Float16* encH = (_Float16*)d_ws;
    convert_f32_f16<<<dim3((unsigned)(encN / 8 / 256)), dim3(256), 0, stream>>>(enc, encH);
    attn_v12<true><<<grid, block, 0, stream>>>(hid, enc, encH, out);
  } else {
    attn_v12<false><<<grid, block, 0, stream>>>(hid, enc, nullptr, out);
  }
}